// Round 10
// baseline (130.903 us; speedup 1.0000x reference)
//
#include <hip/hip_runtime.h>
#include <hip/hip_bf16.h>

#define N_NODES 1536
#define NF 64
#define NOUT 64
#define FIN 65
#define TI 12

typedef __bf16 bf16x8 __attribute__((ext_vector_type(8)));
typedef float f32x4 __attribute__((ext_vector_type(4)));

// One block: TI=12 i-rows x 128 j-cols. Swapped-operand MFMA
//   D[o][j] = sum_k W[o][k] * |feat[j][k]-feat[i][k]|
// TI=12 -> 1536 blocks at 3 blocks/CU (launch_bounds(256,3)) = EXACTLY 2
// dispatch rounds: fewer latency-bound setup phases (whose scattered HBM
// reads force read/write turnarounds on the otherwise pure write stream)
// and zero tail quantization. Output stores are nontemporal (never
// re-read; keeps feat/adj L2-resident). All global loads hoisted out of
// the i-loop (adj+feat slabs in LDS); loop body has only DS ops + stores.
// Epilogue transposes each wave's 32j x 64o tile through wave-private
// XOR-swizzled LDS so global stores are 1 KB lane-contiguous full lines.
__global__ __launch_bounds__(256, 3)
void edge_gcn_mfma(const float* __restrict__ feat,
                   const float* __restrict__ adj,
                   const float* __restrict__ W,
                   const float* __restrict__ b,
                   float* __restrict__ out)
{
    const int tid  = threadIdx.x;
    const int lane = tid & 63;
    const int wv   = tid >> 6;          // wave 0..3
    const int l15  = lane & 15;
    const int lg   = lane >> 4;         // 0..3

    const int i0 = blockIdx.y * TI;
    const int j0 = blockIdx.x * 128;
    const int jw = j0 + wv * 32;        // this wave's 32 j's

    __shared__ float lds[8192];         // 4 waves x 8 KB transpose buffers
    __shared__ float fslab[TI * NF];    // 12 x 64 feat i-slab (3 KB)
    __shared__ float aslab[TI * 128];   // 12 x 128 adj tile (6 KB)
    float* const lbase = lds + wv * 2048;

    // ---- cooperative feat i-slab load: 12 rows x 64 f32 = 192 f32x4 ----
    if (tid < 192) {
        const int row = tid >> 4;            // 0..11
        const int col = (tid & 15) * 4;      // 0..60
        *reinterpret_cast<f32x4*>(&fslab[row * NF + col]) =
            *reinterpret_cast<const f32x4*>(&feat[(size_t)(i0 + row) * NF + col]);
    }
    // ---- cooperative adj tile load: 12 rows x 128 f32 = 384 f32x4 ----
    {
        const int row = tid >> 5;            // 0..7
        const int col = (tid & 31) * 4;      // 0..124
        *reinterpret_cast<f32x4*>(&aslab[row * 128 + col]) =
            *reinterpret_cast<const f32x4*>(
                &adj[(size_t)(i0 + row) * N_NODES + j0 + col]);
        if (tid < 128) {
            const int row2 = 8 + (tid >> 5); // 8..11
            *reinterpret_cast<f32x4*>(&aslab[row2 * 128 + col]) =
                *reinterpret_cast<const f32x4*>(
                    &adj[(size_t)(i0 + row2) * N_NODES + j0 + col]);
        }
    }

    // ---- A fragments (W): once per block ----
    bf16x8 afrag[2][4];                 // [kk][mo]
#pragma unroll
    for (int kk = 0; kk < 2; ++kk) {
#pragma unroll
        for (int mo = 0; mo < 4; ++mo) {
            const float* wp = W + (mo * 16 + l15) * FIN + kk * 32 + lg * 8;
#pragma unroll
            for (int e = 0; e < 8; ++e) afrag[kk][mo][e] = (__bf16)wp[e];
        }
    }

    // ---- feat[j] fragments: once per block ----
    float fjr[2][2][8];                 // [n][kk][e]
#pragma unroll
    for (int n = 0; n < 2; ++n) {
        const float* fjrow = feat + (jw + n * 16 + l15) * NF;
#pragma unroll
        for (int kk = 0; kk < 2; ++kk)
#pragma unroll
            for (int e = 0; e < 8; ++e)
                fjr[n][kk][e] = fjrow[kk * 32 + lg * 8 + e];
    }

    // ---- epilogue-B constants: o = l15*4 + r ----
    float wlB[4], bvB[4];
#pragma unroll
    for (int r = 0; r < 4; ++r) {
        wlB[r] = W[(l15 * 4 + r) * FIN + NF];
        bvB[r] = b[l15 * 4 + r];
    }

    __syncthreads();                    // slabs ready; only barrier

    // ---- i loop (rolled: low VGPR; body has NO global loads) ----
#pragma unroll 1
    for (int ii = 0; ii < TI; ++ii) {
        const int i = i0 + ii;

        float fi[2][8];                 // from LDS (broadcast, conflict-free)
#pragma unroll
        for (int kk = 0; kk < 2; ++kk) {
            const float* fp = &fslab[ii * NF + kk * 32 + lg * 8];
#pragma unroll
            for (int e = 0; e < 8; ++e) fi[kk][e] = fp[e];
        }

        f32x4 acc[4][2];                // [mo][n]
#pragma unroll
        for (int mo = 0; mo < 4; ++mo)
#pragma unroll
            for (int n = 0; n < 2; ++n)
                acc[mo][n] = (f32x4){0.f, 0.f, 0.f, 0.f};

#pragma unroll
        for (int n = 0; n < 2; ++n) {
#pragma unroll
            for (int kk = 0; kk < 2; ++kk) {
                bf16x8 bfrag;
#pragma unroll
                for (int e = 0; e < 8; ++e)
                    bfrag[e] = (__bf16)fabsf(fjr[n][kk][e] - fi[kk][e]);
#pragma unroll
                for (int mo = 0; mo < 4; ++mo)
                    acc[mo][n] = __builtin_amdgcn_mfma_f32_16x16x32_bf16(
                        afrag[kk][mo], bfrag, acc[mo][n], 0, 0, 0);
            }
        }

        // ---- epilogue A: raw acc -> transposed LDS tile ----
        // tile T[j(32)][o(64)], float off = j*64 + (o ^ ((j&7)<<2))
#pragma unroll
        for (int n = 0; n < 2; ++n) {
            const int jrow = n * 16 + l15;
#pragma unroll
            for (int mo = 0; mo < 4; ++mo) {
                const int swz = (mo * 16 + lg * 4) ^ ((l15 & 7) << 2);
                *reinterpret_cast<f32x4*>(lbase + jrow * 64 + swz) = acc[mo][n];
            }
        }

        // ---- epilogue B: finalize (+adj*W64 +bias) + nt 1 KB stores ----
#pragma unroll
        for (int t = 0; t < 8; ++t) {
            const int jr = t * 4 + lg;
            const int oo = l15 * 4;
            f32x4 v = *reinterpret_cast<const f32x4*>(
                lbase + jr * 64 + (oo ^ ((jr & 7) << 2)));
            const float av = aslab[ii * 128 + wv * 32 + jr];
#pragma unroll
            for (int r = 0; r < 4; ++r)
                v[r] = v[r] + av * wlB[r] + bvB[r];
            float* op = out + ((size_t)i * N_NODES + jw + jr) * NOUT + oo;
            __builtin_nontemporal_store(v, reinterpret_cast<f32x4*>(op));
        }
    }
}

extern "C" void kernel_launch(void* const* d_in, const int* in_sizes, int n_in,
                              void* d_out, int out_size, void* d_ws, size_t ws_size,
                              hipStream_t stream) {
    const float* feat = (const float*)d_in[0];   // [1536][64]
    const float* adj  = (const float*)d_in[1];   // [1536][1536]
    const float* W    = (const float*)d_in[2];   // [64][65]
    const float* b    = (const float*)d_in[3];   // [64]
    float* out = (float*)d_out;                  // [1536*1536][64]

    dim3 grid(N_NODES / 128, N_NODES / TI);
    dim3 block(256);
    edge_gcn_mfma<<<grid, block, 0, stream>>>(feat, adj, W, b, out);
}

// Round 11
// 122.222 us; speedup vs baseline: 1.0710x; 1.0710x over previous
//
#include <hip/hip_runtime.h>
#include <hip/hip_bf16.h>

#define N_NODES 1536
#define NF 64
#define NOUT 64
#define FIN 65
#define TI 24

typedef __bf16 bf16x8 __attribute__((ext_vector_type(8)));
typedef float f32x4 __attribute__((ext_vector_type(4)));

// One block: TI=24 i-rows x 128 j-cols. Swapped-operand MFMA
//   D[o][j] = sum_k W[o][k] * |feat[j][k]-feat[i][k]|
// ONE dispatch round: 768 blocks = exactly 3/CU (launch_bounds(256,3)).
// Every global READ the block will ever need (adj 12KB + feat 6KB slabs,
// W, bias) happens once at kernel start; after the single barrier the
// machine runs a pure, uninterrupted 604 MB write stream (no mid-kernel
// HBM reads -> no read/write turnarounds, no round-boundary setup gaps).
// Epilogue transposes each wave's 32j x 64o tile through wave-private
// XOR-swizzled LDS so global stores are 1 KB lane-contiguous full lines.
// LDS: 32 (transpose) + 6 (fslab) + 12 (aslab) = 50 KB; x3 blocks = 150KB/CU.
__global__ __launch_bounds__(256, 3)
void edge_gcn_mfma(const float* __restrict__ feat,
                   const float* __restrict__ adj,
                   const float* __restrict__ W,
                   const float* __restrict__ b,
                   float* __restrict__ out)
{
    const int tid  = threadIdx.x;
    const int lane = tid & 63;
    const int wv   = tid >> 6;          // wave 0..3
    const int l15  = lane & 15;
    const int lg   = lane >> 4;         // 0..3

    const int i0 = blockIdx.y * TI;
    const int j0 = blockIdx.x * 128;
    const int jw = j0 + wv * 32;        // this wave's 32 j's

    __shared__ float lds[8192];         // 4 waves x 8 KB transpose buffers
    __shared__ float fslab[TI * NF];    // 24 x 64 feat i-slab (6 KB)
    __shared__ float aslab[TI * 128];   // 24 x 128 adj tile (12 KB)
    float* const lbase = lds + wv * 2048;

    // ---- cooperative feat i-slab load: 24 rows x 64 f32 = 384 f32x4 ----
#pragma unroll
    for (int h = 0; h < 2; ++h) {
        const int idx = h * 256 + tid;       // 0..511, need 384
        if (idx < 384) {
            const int row = idx >> 4;        // 0..23
            const int col = (idx & 15) * 4;  // 0..60
            *reinterpret_cast<f32x4*>(&fslab[row * NF + col]) =
                *reinterpret_cast<const f32x4*>(
                    &feat[(size_t)(i0 + row) * NF + col]);
        }
    }
    // ---- cooperative adj tile load: 24 rows x 128 f32 = 768 f32x4 ----
#pragma unroll
    for (int h = 0; h < 3; ++h) {
        const int idx = h * 256 + tid;       // 0..767
        const int row = idx >> 5;            // 0..23
        const int col = (idx & 31) * 4;      // 0..124
        *reinterpret_cast<f32x4*>(&aslab[row * 128 + col]) =
            *reinterpret_cast<const f32x4*>(
                &adj[(size_t)(i0 + row) * N_NODES + j0 + col]);
    }

    // ---- A fragments (W): once per block ----
    bf16x8 afrag[2][4];                 // [kk][mo]
#pragma unroll
    for (int kk = 0; kk < 2; ++kk) {
#pragma unroll
        for (int mo = 0; mo < 4; ++mo) {
            const float* wp = W + (mo * 16 + l15) * FIN + kk * 32 + lg * 8;
#pragma unroll
            for (int e = 0; e < 8; ++e) afrag[kk][mo][e] = (__bf16)wp[e];
        }
    }

    // ---- feat[j] fragments: once per block ----
    float fjr[2][2][8];                 // [n][kk][e]
#pragma unroll
    for (int n = 0; n < 2; ++n) {
        const float* fjrow = feat + (jw + n * 16 + l15) * NF;
#pragma unroll
        for (int kk = 0; kk < 2; ++kk)
#pragma unroll
            for (int e = 0; e < 8; ++e)
                fjr[n][kk][e] = fjrow[kk * 32 + lg * 8 + e];
    }

    // ---- epilogue-B constants: o = l15*4 + r ----
    float wlB[4], bvB[4];
#pragma unroll
    for (int r = 0; r < 4; ++r) {
        wlB[r] = W[(l15 * 4 + r) * FIN + NF];
        bvB[r] = b[l15 * 4 + r];
    }

    __syncthreads();                    // slabs ready; only barrier

    // ---- i loop (rolled: low VGPR; body has NO global loads) ----
#pragma unroll 1
    for (int ii = 0; ii < TI; ++ii) {
        const int i = i0 + ii;

        float fi[2][8];                 // from LDS (broadcast, conflict-free)
#pragma unroll
        for (int kk = 0; kk < 2; ++kk) {
            const float* fp = &fslab[ii * NF + kk * 32 + lg * 8];
#pragma unroll
            for (int e = 0; e < 8; ++e) fi[kk][e] = fp[e];
        }

        f32x4 acc[4][2];                // [mo][n]
#pragma unroll
        for (int mo = 0; mo < 4; ++mo)
#pragma unroll
            for (int n = 0; n < 2; ++n)
                acc[mo][n] = (f32x4){0.f, 0.f, 0.f, 0.f};

#pragma unroll
        for (int n = 0; n < 2; ++n) {
#pragma unroll
            for (int kk = 0; kk < 2; ++kk) {
                bf16x8 bfrag;
#pragma unroll
                for (int e = 0; e < 8; ++e)
                    bfrag[e] = (__bf16)fabsf(fjr[n][kk][e] - fi[kk][e]);
#pragma unroll
                for (int mo = 0; mo < 4; ++mo)
                    acc[mo][n] = __builtin_amdgcn_mfma_f32_16x16x32_bf16(
                        afrag[kk][mo], bfrag, acc[mo][n], 0, 0, 0);
            }
        }

        // ---- epilogue A: raw acc -> transposed LDS tile ----
        // tile T[j(32)][o(64)], float off = j*64 + (o ^ ((j&7)<<2))
#pragma unroll
        for (int n = 0; n < 2; ++n) {
            const int jrow = n * 16 + l15;
#pragma unroll
            for (int mo = 0; mo < 4; ++mo) {
                const int swz = (mo * 16 + lg * 4) ^ ((l15 & 7) << 2);
                *reinterpret_cast<f32x4*>(lbase + jrow * 64 + swz) = acc[mo][n];
            }
        }

        // ---- epilogue B: finalize (+adj*W64 +bias) + 1 KB stores ----
#pragma unroll
        for (int t = 0; t < 8; ++t) {
            const int jr = t * 4 + lg;
            const int oo = l15 * 4;
            f32x4 v = *reinterpret_cast<const f32x4*>(
                lbase + jr * 64 + (oo ^ ((jr & 7) << 2)));
            const float av = aslab[ii * 128 + wv * 32 + jr];
#pragma unroll
            for (int r = 0; r < 4; ++r)
                v[r] = v[r] + av * wlB[r] + bvB[r];
            float* op = out + ((size_t)i * N_NODES + jw + jr) * NOUT + oo;
            *reinterpret_cast<f32x4*>(op) = v;
        }
    }
}

extern "C" void kernel_launch(void* const* d_in, const int* in_sizes, int n_in,
                              void* d_out, int out_size, void* d_ws, size_t ws_size,
                              hipStream_t stream) {
    const float* feat = (const float*)d_in[0];   // [1536][64]
    const float* adj  = (const float*)d_in[1];   // [1536][1536]
    const float* W    = (const float*)d_in[2];   // [64][65]
    const float* b    = (const float*)d_in[3];   // [64]
    float* out = (float*)d_out;                  // [1536*1536][64]

    dim3 grid(N_NODES / 128, N_NODES / TI);
    dim3 block(256);
    edge_gcn_mfma<<<grid, block, 0, stream>>>(feat, adj, W, b, out);
}